// Round 11
// baseline (568.667 us; speedup 1.0000x reference)
//
#include <hip/hip_runtime.h>

typedef _Float16 f16;
typedef _Float16 f16x8 __attribute__((ext_vector_type(8)));
typedef float    f32x4 __attribute__((ext_vector_type(4)));

#define V  32000
#define E  128
#define H  128
#define B  32
#define T  128
#define G3 384   // 3H

// ---------- K0: fc_w (256,V) f32  ->  Bt16 (V,256) f16 (transposed, converted)
__global__ __launch_bounds__(256) void k0_convert_fcw(const float* __restrict__ fc_w,
                                                      f16* __restrict__ Bt16)
{
    int v  = blockIdx.x * 256 + threadIdx.x;   // coalesced across lanes
    int k0 = blockIdx.y * 64;
    for (int kk = 0; kk < 64; kk += 8) {
        f16x8 p;
        #pragma unroll
        for (int e = 0; e < 8; ++e)
            p[e] = (f16)fc_w[(size_t)(k0 + kk + e) * V + v];
        *(f16x8*)(Bt16 + (size_t)v * 256 + (k0 + kk)) = p;
    }
}

// ---------- K1: xg = embedding[x] @ W_ih + b    (B*T, 3H)
__global__ __launch_bounds__(384) void k1_embed_xg(const int* __restrict__ x,
                                                   const float* __restrict__ emb,
                                                   const float* __restrict__ W_ih,
                                                   const float* __restrict__ bias,
                                                   float* __restrict__ xg)
{
    int j = threadIdx.x;
    float w[E];
    #pragma unroll
    for (int k = 0; k < E; ++k) w[k] = W_ih[k * G3 + j];
    float bj = bias[j];

    __shared__ __align__(16) float erow[16][E];
    int row0 = blockIdx.x * 16;
    for (int i = j; i < 16 * E; i += G3) {
        int r = i >> 7, c = i & (E - 1);
        erow[r][c] = emb[(size_t)x[row0 + r] * E + c];
    }
    __syncthreads();
    for (int r = 0; r < 16; ++r) {
        float acc = bj;
        #pragma unroll
        for (int k = 0; k < E; k += 4) {
            f32x4 hv = *(const f32x4*)&erow[r][k];
            acc += hv[0]*w[k] + hv[1]*w[k+1] + hv[2]*w[k+2] + hv[3]*w[k+3];
        }
        xg[(size_t)(row0 + r) * G3 + j] = acc;
    }
}

// ---------- KSEQ v3: scan + score + ONLINE-PREFIX CONTEXT, all in one loop.
// 256 threads = 4 waves (1/SIMD), each thread owns 2 FULL columns of the
// 512-col superspace [W_hh(384) | attn_w(128)] -> w0[128]+w1[128] in VGPRs
// (~280; launch_bounds(256,1) allows 512 -> no spill, no k-split, no part[]).
// Context = prefix-scan: masked softmax ctx[t] = sum_{s<t} e_s h_s / sum e_s;
// threads 0..127 keep running (m,S,ctx_j) updated with (score_{t-1}, h_{t-1,j})
// each step -> no hs_lds, no separate context phase at all.
__global__ __launch_bounds__(256, 1) void kseq(const float* __restrict__ xg,
                                               const float* __restrict__ W_hh,
                                               const float* __restrict__ attn_w,
                                               const float* __restrict__ attn_b,
                                               const float* __restrict__ v_w,
                                               const float* __restrict__ v_b,
                                               f16* __restrict__ A16)
{
    int b    = blockIdx.x;
    int tid  = threadIdx.x;          // 0..255
    int lane = tid & 63;
    bool isGate = (tid < 192);       // waves 0-2: gate cols; wave 3: attn cols
    int c0 = 2 * tid, c1 = 2 * tid + 1;

    float w0[H], w1[H];
    if (isGate) {
        #pragma unroll
        for (int k = 0; k < H; ++k) { w0[k] = W_hh[k * G3 + c0]; w1[k] = W_hh[k * G3 + c1]; }
    } else {
        #pragma unroll
        for (int k = 0; k < H; ++k) { w0[k] = attn_w[k * H + (c0 - G3)]; w1[k] = attn_w[k * H + (c1 - G3)]; }
    }
    float ab0 = 0.f, ab1 = 0.f, vw0 = 0.f, vw1 = 0.f;
    if (!isGate) {
        ab0 = attn_b[c0 - G3]; ab1 = attn_b[c1 - G3];
        vw0 = v_w[c0 - G3];    vw1 = v_w[c1 - G3];
    }
    float vb = v_b[0];

    __shared__ __align__(16) float h[H];
    __shared__ float g[G3];
    __shared__ float pA;
    if (tid < H) h[tid] = 0.0f;
    __syncthreads();

    const float* xgb = xg + (size_t)b * T * G3;
    float xn0 = 0.f, xn1 = 0.f;
    if (isGate) { float2 x0 = *(const float2*)&xgb[c0]; xn0 = x0.x; xn1 = x0.y; }

    // online-softmax prefix state (threads 0..127)
    float m_run = -3.0e38f, S_run = 0.f, ctx = 0.f, hprev = 0.f;

    for (int t = 0; t < T; ++t) {
        // full dot of both columns against h_{t-1} (broadcast LDS reads)
        float a0 = xn0, b0 = 0.f, a1 = xn1, b1 = 0.f;
        if (isGate && t + 1 < T) {
            float2 nx = *(const float2*)&xgb[(size_t)(t + 1) * G3 + c0];
            xn0 = nx.x; xn1 = nx.y;
        }
        #pragma unroll
        for (int k = 0; k < H; k += 8) {
            f32x4 hA = *(const f32x4*)&h[k];
            f32x4 hB = *(const f32x4*)&h[k + 4];
            a0 += hA[0]*w0[k]   + hA[1]*w0[k+1] + hA[2]*w0[k+2] + hA[3]*w0[k+3];
            b0 += hB[0]*w0[k+4] + hB[1]*w0[k+5] + hB[2]*w0[k+6] + hB[3]*w0[k+7];
            a1 += hA[0]*w1[k]   + hA[1]*w1[k+1] + hA[2]*w1[k+2] + hA[3]*w1[k+3];
            b1 += hB[0]*w1[k+4] + hB[1]*w1[k+5] + hB[2]*w1[k+6] + hB[3]*w1[k+7];
        }
        float d0 = a0 + b0, d1 = a1 + b1;

        if (isGate) {
            g[c0] = d0; g[c1] = d1;
        } else {
            // score(h_{t-1}) = sum_j tanh(d_j + ab_j)*vw_j  + vb
            float e0 = __expf(2.0f * (d0 + ab0));
            float e1 = __expf(2.0f * (d1 + ab1));
            float u  = (1.0f - 2.0f / (e0 + 1.0f)) * vw0
                     + (1.0f - 2.0f / (e1 + 1.0f)) * vw1;
            #pragma unroll
            for (int o = 32; o > 0; o >>= 1) u += __shfl_xor(u, o);
            if (lane == 0) pA = u + vb;
        }
        __syncthreads();

        if (tid < H) {
            // ---- context prefix update with (score_{t-1}, h_{t-1,tid})
            float outv = 0.0f;
            if (t > 0) {
                float sc    = pA;
                float mn    = fmaxf(m_run, sc);
                float scale = __expf(m_run - mn);     // 0 at first update (m=-inf)
                float e     = __expf(sc - mn);
                S_run = S_run * scale + e;
                ctx   = ctx   * scale + e * hprev;
                m_run = mn;
                outv  = ctx / S_run;
            }
            A16[((size_t)b * T + t) * 256 + H + tid] = (f16)outv;

            // ---- gate math -> h_t
            float iz  = g[tid], ir = g[tid + 128], in_ = g[tid + 256];
            float z   = 1.0f / (1.0f + __expf(-iz));
            float r   = 1.0f / (1.0f + __expf(-ir));
            float pn  = in_ * r;
            float ex  = __expf(2.0f * pn);
            float n   = 1.0f - 2.0f / (ex + 1.0f);    // tanh(pn)
            float hn  = (1.0f - z) * n + z * hprev;   // hprev == h_{t-1,tid}
            h[tid] = hn;
            hprev  = hn;
            A16[((size_t)b * T + t) * 256 + tid] = (f16)hn;
        }
        __syncthreads();
    }
}

// ---------- K5: out = combined(4096x256) @ fc_w(256xV) + fc_b   via fp16 MFMA.
// 512 blocks, 2/CU, whole grid co-resident. XCD-pinned ni (bid&7); A-tile in
// registers; B chunks (64 cols, 32KB) double-buffered; counted vmcnt(4).
__global__ __launch_bounds__(512, 4) void k5_gemm(const f16* __restrict__ A16,
                                                  const f16* __restrict__ Bt16,
                                                  const float* __restrict__ fc_b,
                                                  float* __restrict__ out)
{
    __shared__ __align__(16) char Bs[2][32768];   // [buf][64 n][512 B k], XOR-swizzled
    int bid  = blockIdx.x;                 // 0..511
    int ni   = ((bid & 7) << 1) | (bid >> 8);   // 0..15, pinned to XCD = bid&7
    int mi   = (bid >> 3) & 31;            // 0..31
    int tid  = threadIdx.x;
    int w    = tid >> 6;                   // wave 0..7
    int lane = tid & 63;
    int l15  = lane & 15;
    int lhi  = lane >> 4;                  // 0..3

    const f16* Ab = A16 + (size_t)(mi * 128 + w * 16 + l15) * 256 + lhi * 8;
    f16x8 a[8];
    #pragma unroll
    for (int kt = 0; kt < 8; ++kt)
        a[kt] = *(const f16x8*)(Ab + kt * 32);

#define STAGE(cc, buf)                                                          \
    {                                                                           \
        const char* src = (const char*)(Bt16 + (size_t)(cc) * 64 * 256);        \
        _Pragma("unroll")                                                       \
        for (int it = 0; it < 4; ++it) {                                        \
            int ck  = it * 8 + w;                                               \
            int lin = ck * 1024 + lane * 16;                                    \
            int row = lin >> 9;                                                 \
            int g   = lin ^ ((row & 7) << 4);                                   \
            __builtin_amdgcn_global_load_lds(                                   \
                (const __attribute__((address_space(1))) void*)(src + g),       \
                (__attribute__((address_space(3))) void*)(&Bs[buf][0] + ck * 1024), \
                16, 0, 0);                                                      \
        }                                                                       \
    }

    STAGE(ni, 0);
    asm volatile("s_waitcnt vmcnt(0)");
    __syncthreads();

    int nc = (500 - ni + 15) >> 4;   // chunks c = ni + 16j < 500
    for (int j = 0; j < nc; ++j) {
        int c   = ni + j * 16;
        int cur = j & 1;

        if (j + 1 < nc) STAGE(c + 16, cur ^ 1);       // prefetch, issued first
        __builtin_amdgcn_sched_barrier(0);

        f32x4 acc[4];
        #pragma unroll
        for (int f = 0; f < 4; ++f)
            acc[f] = *(const f32x4*)(fc_b + c * 64 + f * 16 + lhi * 4);

        const char* bb = &Bs[cur][0];
        #pragma unroll
        for (int kt = 0; kt < 8; ++kt) {
            f16x8 bf[4];
            #pragma unroll
            for (int f = 0; f < 4; ++f) {
                int r  = f * 16 + l15;
                int ad = r * 512 + ((kt * 64 + lhi * 16) ^ ((r & 7) << 4));
                bf[f] = *(const f16x8*)(bb + ad);
            }
            #pragma unroll
            for (int f = 0; f < 4; ++f)
                acc[f] = __builtin_amdgcn_mfma_f32_16x16x32_f16(bf[f], a[kt], acc[f], 0, 0, 0);
        }

        int row = mi * 128 + w * 16 + l15;
        #pragma unroll
        for (int f = 0; f < 4; ++f)
            *(f32x4*)(out + (size_t)row * V + c * 64 + f * 16 + lhi * 4) = acc[f];

        if (j + 1 < nc) {
            __builtin_amdgcn_sched_barrier(0);
            asm volatile("s_waitcnt vmcnt(4)" ::: "memory");
            __builtin_amdgcn_s_barrier();
            __builtin_amdgcn_sched_barrier(0);
        }
    }
#undef STAGE
}

extern "C" void kernel_launch(void* const* d_in, const int* in_sizes, int n_in,
                              void* d_out, int out_size, void* d_ws, size_t ws_size,
                              hipStream_t stream)
{
    (void)in_sizes; (void)n_in; (void)out_size; (void)ws_size;
    const int*   x      = (const int*)  d_in[0];
    const float* emb    = (const float*)d_in[1];
    const float* W_ih   = (const float*)d_in[2];
    const float* W_hh   = (const float*)d_in[3];
    const float* bias   = (const float*)d_in[4];
    const float* attn_w = (const float*)d_in[5];
    const float* attn_b = (const float*)d_in[6];
    const float* v_w    = (const float*)d_in[7];
    const float* v_b    = (const float*)d_in[8];
    const float* fc_w   = (const float*)d_in[9];
    const float* fc_b   = (const float*)d_in[10];
    float* out = (float*)d_out;

    char* ws = (char*)d_ws;
    float* xg     = (float*)(ws);              // 4096*384*4 = 6,291,456 B
    f16*   A16    = (f16*)  (ws + 8404992);    // 4096*256*2 = 2,097,152 B
    f16*   Bt16   = (f16*)  (ws + 10502144);   // 32000*256*2 = 16,384,000 B

    hipLaunchKernelGGL(k0_convert_fcw, dim3(V / 256, 4), dim3(256), 0, stream, fc_w, Bt16);
    hipLaunchKernelGGL(k1_embed_xg,    dim3(B * T / 16), dim3(G3),  0, stream, x, emb, W_ih, bias, xg);
    hipLaunchKernelGGL(kseq,           dim3(B),          dim3(256), 0, stream,
                       xg, W_hh, attn_w, attn_b, v_w, v_b, A16);
    hipLaunchKernelGGL(k5_gemm,        dim3(512),        dim3(512), 0, stream, A16, Bt16, fc_b, out);
}

// Round 12
// 417.651 us; speedup vs baseline: 1.3616x; 1.3616x over previous
//
#include <hip/hip_runtime.h>

typedef _Float16 f16;
typedef _Float16 f16x8 __attribute__((ext_vector_type(8)));
typedef float    f32x4 __attribute__((ext_vector_type(4)));

#define V  32000
#define E  128
#define H  128
#define B  32
#define T  128
#define G3 384   // 3H

// ---------- K0: fc_w (256,V) f32  ->  Bt16 (V,256) f16 (transposed, converted)
__global__ __launch_bounds__(256) void k0_convert_fcw(const float* __restrict__ fc_w,
                                                      f16* __restrict__ Bt16)
{
    int v  = blockIdx.x * 256 + threadIdx.x;   // coalesced across lanes
    int k0 = blockIdx.y * 64;
    for (int kk = 0; kk < 64; kk += 8) {
        f16x8 p;
        #pragma unroll
        for (int e = 0; e < 8; ++e)
            p[e] = (f16)fc_w[(size_t)(k0 + kk + e) * V + v];
        *(f16x8*)(Bt16 + (size_t)v * 256 + (k0 + kk)) = p;
    }
}

// ---------- K1: xg = embedding[x] @ W_ih + b    (B*T, 3H)
__global__ __launch_bounds__(384) void k1_embed_xg(const int* __restrict__ x,
                                                   const float* __restrict__ emb,
                                                   const float* __restrict__ W_ih,
                                                   const float* __restrict__ bias,
                                                   float* __restrict__ xg)
{
    int j = threadIdx.x;
    float w[E];
    #pragma unroll
    for (int k = 0; k < E; ++k) w[k] = W_ih[k * G3 + j];
    float bj = bias[j];

    __shared__ __align__(16) float erow[16][E];
    int row0 = blockIdx.x * 16;
    for (int i = j; i < 16 * E; i += G3) {
        int r = i >> 7, c = i & (E - 1);
        erow[r][c] = emb[(size_t)x[row0 + r] * E + c];
    }
    __syncthreads();
    for (int r = 0; r < 16; ++r) {
        float acc = bj;
        #pragma unroll
        for (int k = 0; k < E; k += 4) {
            f32x4 hv = *(const f32x4*)&erow[r][k];
            acc += hv[0]*w[k] + hv[1]*w[k+1] + hv[2]*w[k+2] + hv[3]*w[k+3];
        }
        xg[(size_t)(row0 + r) * G3 + j] = acc;
    }
}

// ---------- KSEQ v4: v3's (passing) math on k2's proven register budget.
// 512 threads, ONE full column per thread: w[128] ~ 160 VGPR (the R5-R7 k2
// regime -- never spilled). Waves 0-5: the 384 gate columns. Waves 6-7: the
// 128 attn columns (score reduce via 2-entry pA, as v2). Online-prefix
// context (threads 0..127) identical to v3. No k-split, no part[] round-trip.
__global__ __launch_bounds__(512, 1) void kseq(const float* __restrict__ xg,
                                               const float* __restrict__ W_hh,
                                               const float* __restrict__ attn_w,
                                               const float* __restrict__ attn_b,
                                               const float* __restrict__ v_w,
                                               const float* __restrict__ v_b,
                                               f16* __restrict__ A16)
{
    int b    = blockIdx.x;
    int tid  = threadIdx.x;          // 0..511
    int lane = tid & 63;
    int wv   = tid >> 6;             // wave 0..7
    bool isGate = (tid < G3);

    float w[H];
    if (isGate) {
        #pragma unroll
        for (int k = 0; k < H; ++k) w[k] = W_hh[k * G3 + tid];
    } else {
        #pragma unroll
        for (int k = 0; k < H; ++k) w[k] = attn_w[k * H + (tid - G3)];
    }
    float ab = 0.f, vwgt = 0.f;
    if (!isGate) { ab = attn_b[tid - G3]; vwgt = v_w[tid - G3]; }
    float vb = v_b[0];

    __shared__ __align__(16) float h[H];
    __shared__ float g[G3];
    __shared__ float pA[2];
    if (tid < H) h[tid] = 0.0f;
    __syncthreads();

    const float* xgb = xg + (size_t)b * T * G3;
    float xnext = isGate ? xgb[tid] : 0.0f;

    // online-softmax prefix state (threads 0..127)
    float m_run = -3.0e38f, S_run = 0.f, ctx = 0.f, hprev = 0.f;

    for (int t = 0; t < T; ++t) {
        // full dot of this thread's column against h_{t-1} (broadcast LDS reads)
        float s0 = xnext, s1 = 0.f, s2 = 0.f, s3 = 0.f;
        if (isGate && t + 1 < T) xnext = xgb[(size_t)(t + 1) * G3 + tid];
        #pragma unroll
        for (int k = 0; k < H; k += 16) {
            f32x4 h0 = *(const f32x4*)&h[k];
            f32x4 h1 = *(const f32x4*)&h[k + 4];
            f32x4 h2 = *(const f32x4*)&h[k + 8];
            f32x4 h3 = *(const f32x4*)&h[k + 12];
            s0 += h0[0]*w[k]    + h0[1]*w[k+1]  + h0[2]*w[k+2]  + h0[3]*w[k+3];
            s1 += h1[0]*w[k+4]  + h1[1]*w[k+5]  + h1[2]*w[k+6]  + h1[3]*w[k+7];
            s2 += h2[0]*w[k+8]  + h2[1]*w[k+9]  + h2[2]*w[k+10] + h2[3]*w[k+11];
            s3 += h3[0]*w[k+12] + h3[1]*w[k+13] + h3[2]*w[k+14] + h3[3]*w[k+15];
        }
        float d = (s0 + s1) + (s2 + s3);

        if (isGate) {
            g[tid] = d;
        } else {
            // score(h_{t-1}) contribution: tanh(d + ab) * vw ; 2-wave reduce
            float ex = __expf(2.0f * (d + ab));
            float u  = (1.0f - 2.0f / (ex + 1.0f)) * vwgt;
            #pragma unroll
            for (int o = 32; o > 0; o >>= 1) u += __shfl_xor(u, o);
            if (lane == 0) pA[wv - 6] = u;
        }
        __syncthreads();

        if (tid < H) {
            // ---- context prefix update with (score_{t-1}, h_{t-1,tid})
            float outv = 0.0f;
            if (t > 0) {
                float sc    = pA[0] + pA[1] + vb;
                float mn    = fmaxf(m_run, sc);
                float scale = __expf(m_run - mn);     // 0 at first update (m=-inf)
                float e     = __expf(sc - mn);
                S_run = S_run * scale + e;
                ctx   = ctx   * scale + e * hprev;
                m_run = mn;
                outv  = ctx / S_run;
            }
            A16[((size_t)b * T + t) * 256 + H + tid] = (f16)outv;

            // ---- gate math -> h_t
            float iz  = g[tid], ir = g[tid + 128], in_ = g[tid + 256];
            float z   = 1.0f / (1.0f + __expf(-iz));
            float r   = 1.0f / (1.0f + __expf(-ir));
            float pn  = in_ * r;
            float ex  = __expf(2.0f * pn);
            float n   = 1.0f - 2.0f / (ex + 1.0f);    // tanh(pn)
            float hn  = (1.0f - z) * n + z * hprev;   // hprev == h_{t-1,tid}
            h[tid] = hn;
            hprev  = hn;
            A16[((size_t)b * T + t) * 256 + tid] = (f16)hn;
        }
        __syncthreads();
    }
}

// ---------- K5 v2: 256 threads / 4 waves, 32 rows per wave (2 A-tiles).
// Every B fragment read from LDS now feeds TWO MFMAs -> LDS-read cycles per
// FLOP halved vs the 16-row version (ds_read_b128 ~12cyc was ~45% of k5).
// Still 2 blocks/CU (64KB LDS). XCD-pinned ni; counted vmcnt(8).
__global__ __launch_bounds__(256, 2) void k5_gemm(const f16* __restrict__ A16,
                                                  const f16* __restrict__ Bt16,
                                                  const float* __restrict__ fc_b,
                                                  float* __restrict__ out)
{
    __shared__ __align__(16) char Bs[2][32768];   // [buf][64 n][512 B k], XOR-swizzled
    int bid  = blockIdx.x;                 // 0..511
    int ni   = ((bid & 7) << 1) | (bid >> 8);   // 0..15, pinned to XCD = bid&7
    int mi   = (bid >> 3) & 31;            // 0..31
    int tid  = threadIdx.x;
    int w    = tid >> 6;                   // wave 0..3
    int lane = tid & 63;
    int l15  = lane & 15;
    int lhi  = lane >> 4;                  // 0..3

    // ---- A fragments: wave w owns rows mi*128 + w*32 + mf*16 + l15 (64 VGPR)
    const f16* Ab = A16 + (size_t)(mi * 128 + w * 32 + l15) * 256 + lhi * 8;
    f16x8 a[2][8];
    #pragma unroll
    for (int mf = 0; mf < 2; ++mf)
        #pragma unroll
        for (int kt = 0; kt < 8; ++kt)
            a[mf][kt] = *(const f16x8*)(Ab + mf * 16 * 256 + kt * 32);

    // stage chunk cc (64 cols = 32KB): 256 thr x 8 x 16B; swizzled source
#define STAGE(cc, buf)                                                          \
    {                                                                           \
        const char* src = (const char*)(Bt16 + (size_t)(cc) * 64 * 256);        \
        _Pragma("unroll")                                                       \
        for (int it = 0; it < 8; ++it) {                                        \
            int ck  = it * 4 + w;                                               \
            int lin = ck * 1024 + lane * 16;                                    \
            int row = lin >> 9;                                                 \
            int g   = lin ^ ((row & 7) << 4);                                   \
            __builtin_amdgcn_global_load_lds(                                   \
                (const __attribute__((address_space(1))) void*)(src + g),       \
                (__attribute__((address_space(3))) void*)(&Bs[buf][0] + ck * 1024), \
                16, 0, 0);                                                      \
        }                                                                       \
    }

    STAGE(ni, 0);
    asm volatile("s_waitcnt vmcnt(0)");
    __syncthreads();

    int nc = (500 - ni + 15) >> 4;   // chunks c = ni + 16j < 500
    for (int j = 0; j < nc; ++j) {
        int c   = ni + j * 16;
        int cur = j & 1;

        if (j + 1 < nc) STAGE(c + 16, cur ^ 1);       // prefetch, issued first
        __builtin_amdgcn_sched_barrier(0);

        f32x4 acc[2][4];
        #pragma unroll
        for (int f = 0; f < 4; ++f) {
            f32x4 bv = *(const f32x4*)(fc_b + c * 64 + f * 16 + lhi * 4);
            acc[0][f] = bv;
            acc[1][f] = bv;
        }

        const char* bb = &Bs[cur][0];
        #pragma unroll
        for (int kt = 0; kt < 8; ++kt) {
            f16x8 bf[4];
            #pragma unroll
            for (int f = 0; f < 4; ++f) {
                int r  = f * 16 + l15;
                int ad = r * 512 + ((kt * 64 + lhi * 16) ^ ((r & 7) << 4));
                bf[f] = *(const f16x8*)(bb + ad);
            }
            #pragma unroll
            for (int mf = 0; mf < 2; ++mf)
                #pragma unroll
                for (int f = 0; f < 4; ++f)
                    acc[mf][f] = __builtin_amdgcn_mfma_f32_16x16x32_f16(bf[f], a[mf][kt], acc[mf][f], 0, 0, 0);
        }

        // stores: row = mi*128 + w*32 + mf*16 + l15, col = c*64 + f*16 + lhi*4
        #pragma unroll
        for (int mf = 0; mf < 2; ++mf) {
            int row = mi * 128 + w * 32 + mf * 16 + l15;
            #pragma unroll
            for (int f = 0; f < 4; ++f)
                *(f32x4*)(out + (size_t)row * V + c * 64 + f * 16 + lhi * 4) = acc[mf][f];
        }

        if (j + 1 < nc) {
            // wait only for the 8 prefetch loads (oldest); 8 stores stay in flight
            __builtin_amdgcn_sched_barrier(0);
            asm volatile("s_waitcnt vmcnt(8)" ::: "memory");
            __builtin_amdgcn_s_barrier();
            __builtin_amdgcn_sched_barrier(0);
        }
    }
#undef STAGE
}

extern "C" void kernel_launch(void* const* d_in, const int* in_sizes, int n_in,
                              void* d_out, int out_size, void* d_ws, size_t ws_size,
                              hipStream_t stream)
{
    (void)in_sizes; (void)n_in; (void)out_size; (void)ws_size;
    const int*   x      = (const int*)  d_in[0];
    const float* emb    = (const float*)d_in[1];
    const float* W_ih   = (const float*)d_in[2];
    const float* W_hh   = (const float*)d_in[3];
    const float* bias   = (const float*)d_in[4];
    const float* attn_w = (const float*)d_in[5];
    const float* attn_b = (const float*)d_in[6];
    const float* v_w    = (const float*)d_in[7];
    const float* v_b    = (const float*)d_in[8];
    const float* fc_w   = (const float*)d_in[9];
    const float* fc_b   = (const float*)d_in[10];
    float* out = (float*)d_out;

    char* ws = (char*)d_ws;
    float* xg     = (float*)(ws);              // 4096*384*4 = 6,291,456 B
    f16*   A16    = (f16*)  (ws + 8404992);    // 4096*256*2 = 2,097,152 B
    f16*   Bt16   = (f16*)  (ws + 10502144);   // 32000*256*2 = 16,384,000 B

    hipLaunchKernelGGL(k0_convert_fcw, dim3(V / 256, 4), dim3(256), 0, stream, fc_w, Bt16);
    hipLaunchKernelGGL(k1_embed_xg,    dim3(B * T / 16), dim3(G3),  0, stream, x, emb, W_ih, bias, xg);
    hipLaunchKernelGGL(kseq,           dim3(B),          dim3(512), 0, stream,
                       xg, W_hh, attn_w, attn_b, v_w, v_b, A16);
    hipLaunchKernelGGL(k5_gemm,        dim3(512),        dim3(256), 0, stream, A16, Bt16, fc_b, out);
}